// Round 1
// baseline (349.063 us; speedup 1.0000x reference)
//
#include <hip/hip_runtime.h>

#define T_SEQ 8192
#define E_DIM 1024
#define D_DIM 11
#define QKV_STRIDE 36   // [k:0..10][pad:11][q:12..22][pad:23][v:24..34][pad:35]

// ---------------------------------------------------------------------------
// K0: pad Wf [E][11] -> [E][12] (zero col 11) so epilogue can float4-load rows
// ---------------------------------------------------------------------------
__global__ __launch_bounds__(256) void prep_wf(const float* __restrict__ Wf,
                                               float* __restrict__ Wfp) {
    int id = blockIdx.x * 256 + threadIdx.x;      // 0 .. E*12-1
    if (id >= E_DIM * 12) return;
    int e = id / 12, d = id % 12;
    Wfp[id] = (d < D_DIM) ? Wf[(size_t)e * D_DIM + d] : 0.f;
}

// ---------------------------------------------------------------------------
// K1: qkv projection. Block = 256 threads = 4 waves. lane = row (64 rows per
// block), wave = group of 9 outputs (36 slots: 33 real + 3 dummy). Weights are
// wave-uniform -> scalar-operand FMAs. grid.y splits E in halves; partial
// sums combine via atomicAdd into the zeroed qkv buffer.
// ---------------------------------------------------------------------------
__global__ __launch_bounds__(256) void qkv_proj(
    const float* __restrict__ xe,
    const float* __restrict__ Wk, const float* __restrict__ bk,
    const float* __restrict__ Wq, const float* __restrict__ bq,
    const float* __restrict__ Wv, const float* __restrict__ bv,
    float* __restrict__ qkv) {
    const int lane = threadIdx.x & 63;
    const int w = __builtin_amdgcn_readfirstlane(threadIdx.x >> 6);
    const int t = blockIdx.x * 64 + lane;
    const int half = blockIdx.y;                  // E cols [half*512, half*512+512)

    const float4* xp = (const float4*)(xe + (size_t)t * E_DIM) + half * 128;

    float acc[9];
    const float* wr[9];
    int col[9];
    bool live[9];
#pragma unroll
    for (int k = 0; k < 9; ++k) {
        int o = w * 9 + k;
        const float* base; float b; int c; bool lv = true;
        if (o < 11)      { base = Wk + (size_t)o * E_DIM;        b = bk[o];      c = o; }
        else if (o < 22) { base = Wq + (size_t)(o - 11) * E_DIM; b = bq[o - 11]; c = 12 + (o - 11); }
        else if (o < 33) { base = Wv + (size_t)(o - 22) * E_DIM; b = bv[o - 22]; c = 24 + (o - 22); }
        else             { base = Wk; b = 0.f; c = 0; lv = false; }
        wr[k] = base + half * 512;
        acc[k] = (half == 0) ? b : 0.f;           // bias added exactly once
        col[k] = c;
        live[k] = lv;
    }

    for (int c4 = 0; c4 < 128; ++c4) {
        float4 xv = xp[c4];
#pragma unroll
        for (int k = 0; k < 9; ++k) {
            const float* wp = wr[k] + c4 * 4;
            acc[k] += xv.x * wp[0] + xv.y * wp[1] + xv.z * wp[2] + xv.w * wp[3];
        }
    }

    float* dst = qkv + (size_t)t * QKV_STRIDE;
#pragma unroll
    for (int k = 0; k < 9; ++k)
        if (live[k]) atomicAdd(dst + col[k], acc[k]);
}

// ---------------------------------------------------------------------------
// K2: causal attention, flash-style with j-split. Thread owns row i
// (block = rows [ib*256, ib*256+256)); grid.y = j-chunk of 128 columns.
// No online max needed: |s| <~ 25 so exp(s) cannot overflow fp32, and the
// per-chunk partial (sum exp, sum exp*v) combines by plain addition ->
// atomicAdd into accum[T][12] (cols 0..10 = o, col 11 = l).
// ---------------------------------------------------------------------------
__global__ __launch_bounds__(256) void attn(const float* __restrict__ qkv,
                                            float* __restrict__ accum) {
    const int ib = blockIdx.x, jc = blockIdx.y;
    if (jc > 2 * ib + 1) return;                  // chunk entirely above diagonal
    const int i = ib * 256 + threadIdx.x;

    const float4* qp = (const float4*)(qkv + (size_t)i * QKV_STRIDE + 12);
    const float4 q0 = qp[0], q1 = qp[1], q2 = qp[2];

    float o00 = 0.f, o01 = 0.f, o02 = 0.f, o03 = 0.f, o04 = 0.f, o05 = 0.f,
          o06 = 0.f, o07 = 0.f, o08 = 0.f, o09 = 0.f, o10 = 0.f, l = 0.f;

    const int j0 = jc * 128;
    const float4* kvp = (const float4*)(qkv + (size_t)j0 * QKV_STRIDE);

    for (int jj = 0; jj < 128; ++jj) {
        const float4 k0 = kvp[0], k1 = kvp[1], k2 = kvp[2];
        const float4 v0 = kvp[6], v1 = kvp[7], v2 = kvp[8];
        kvp += 9;
        float s = ((q0.x * k0.x + q0.y * k0.y) + (q0.z * k0.z + q0.w * k0.w))
                + ((q1.x * k1.x + q1.y * k1.y) + (q1.z * k1.z + q1.w * k1.w))
                + ((q2.x * k2.x + q2.y * k2.y) + q2.z * k2.z);
        float p = (j0 + jj <= i) ? __expf(s) : 0.f;
        l   += p;
        o00 += p * v0.x; o01 += p * v0.y; o02 += p * v0.z; o03 += p * v0.w;
        o04 += p * v1.x; o05 += p * v1.y; o06 += p * v1.z; o07 += p * v1.w;
        o08 += p * v2.x; o09 += p * v2.y; o10 += p * v2.z;
    }

    float* a = accum + (size_t)i * 12;
    atomicAdd(a + 0, o00);  atomicAdd(a + 1, o01);  atomicAdd(a + 2, o02);
    atomicAdd(a + 3, o03);  atomicAdd(a + 4, o04);  atomicAdd(a + 5, o05);
    atomicAdd(a + 6, o06);  atomicAdd(a + 7, o07);  atomicAdd(a + 8, o08);
    atomicAdd(a + 9, o09);  atomicAdd(a + 10, o10); atomicAdd(a + 11, l);
}

// ---------------------------------------------------------------------------
// K4: epilogue. out[t][e] = (sum_d o[t][d]*Wf[e][d]) / l[t] + bf[e].
// Block handles 4 rows x all 1024 cols; thread owns 4 consecutive e
// (float4 coalesced store). accum row loads are wave-uniform (scalar).
// ---------------------------------------------------------------------------
__device__ inline float dot11w(const float4* w3, const float* r) {
    return ((w3[0].x * r[0] + w3[0].y * r[1]) + (w3[0].z * r[2] + w3[0].w * r[3]))
         + ((w3[1].x * r[4] + w3[1].y * r[5]) + (w3[1].z * r[6] + w3[1].w * r[7]))
         + ((w3[2].x * r[8] + w3[2].y * r[9]) + w3[2].z * r[10]);
}

__global__ __launch_bounds__(256) void epilogue(const float* __restrict__ accum,
                                                const float* __restrict__ Wfp,
                                                const float* __restrict__ bf,
                                                float* __restrict__ out) {
    const int t0 = blockIdx.x * 4;
    const int e0 = threadIdx.x * 4;

    float4 wf[4][3];
#pragma unroll
    for (int ee = 0; ee < 4; ++ee) {
        const float4* wp = (const float4*)(Wfp + (size_t)(e0 + ee) * 12);
        wf[ee][0] = wp[0]; wf[ee][1] = wp[1]; wf[ee][2] = wp[2];
    }
    const float4 bfe = *(const float4*)(bf + e0);

#pragma unroll
    for (int r = 0; r < 4; ++r) {
        const int t = t0 + r;
        const float* a = accum + (size_t)t * 12;
        const float rl = 1.f / a[11];
        float res[11];
#pragma unroll
        for (int d = 0; d < 11; ++d) res[d] = a[d] * rl;
        float4 ov;
        ov.x = dot11w(wf[0], res) + bfe.x;
        ov.y = dot11w(wf[1], res) + bfe.y;
        ov.z = dot11w(wf[2], res) + bfe.z;
        ov.w = dot11w(wf[3], res) + bfe.w;
        *(float4*)(out + (size_t)t * E_DIM + e0) = ov;
    }
}

// ---------------------------------------------------------------------------
extern "C" void kernel_launch(void* const* d_in, const int* in_sizes, int n_in,
                              void* d_out, int out_size, void* d_ws, size_t ws_size,
                              hipStream_t stream) {
    const float* xe = (const float*)d_in[1];
    const float* Wk = (const float*)d_in[2];
    const float* bk = (const float*)d_in[3];
    const float* Wq = (const float*)d_in[4];
    const float* bq = (const float*)d_in[5];
    const float* Wv = (const float*)d_in[6];
    const float* bv = (const float*)d_in[7];
    const float* Wf = (const float*)d_in[8];
    const float* bf = (const float*)d_in[9];
    float* out = (float*)d_out;

    float* qkv   = (float*)d_ws;                          // T*36 floats
    float* accum = qkv + (size_t)T_SEQ * QKV_STRIDE;      // T*12 floats
    float* wfp   = accum + (size_t)T_SEQ * 12;            // E*12 floats

    hipMemsetAsync(qkv,   0, (size_t)T_SEQ * QKV_STRIDE * sizeof(float), stream);
    hipMemsetAsync(accum, 0, (size_t)T_SEQ * 12 * sizeof(float), stream);

    prep_wf<<<(E_DIM * 12 + 255) / 256, 256, 0, stream>>>(Wf, wfp);
    qkv_proj<<<dim3(T_SEQ / 64, 2), 256, 0, stream>>>(xe, Wk, bk, Wq, bq, Wv, bv, qkv);
    attn<<<dim3(T_SEQ / 256, T_SEQ / 128), 256, 0, stream>>>(qkv, accum);
    epilogue<<<T_SEQ / 4, 256, 0, stream>>>(accum, wfp, bf, out);
}

// Round 2
// 229.644 us; speedup vs baseline: 1.5200x; 1.5200x over previous
//
#include <hip/hip_runtime.h>

#define T_SEQ 8192
#define E_DIM 1024
#define QS 36              // padded qkv row: [k 0..10][pad][q 12..22][pad][v 24..34][pad]
#define NEC 4              // E-chunks in qkv projection
#define ECOLS (E_DIM / NEC)       // 256 cols per chunk
#define JC 128             // attn j-chunk rows
#define NJC (T_SEQ / JC)   // 64
#define RPB 512            // attn rows per block
#define NIB (T_SEQ / RPB)  // 16
#define TR 16              // pass2 rows per block

// ws layout (floats):
//   partQ [NEC][T][QS]  = 1,179,648 f (4.72 MB)
//   qkvF  [T][QS]       =   294,912 f (1.18 MB)
//   part  [NJC][T][12]  = 6,291,456 f (25.2 MB)   total ~31.1 MB

// ---------------------------------------------------------------------------
// K1: qkv projection partials. Block = 1 wave (64 threads) = 64 rows.
// blockIdx = (row-block, E-chunk, output-group). Output-group from blockIdx.z
// so weight addresses are block-uniform -> scalar loads. xe reads are per-lane
// 16B row-major; lines fully consumed across the unrolled c4 loop (L1 absorbs).
// ---------------------------------------------------------------------------
__global__ __launch_bounds__(64) void qkv_proj(
    const float* __restrict__ xe,
    const float* __restrict__ Wk, const float* __restrict__ bk,
    const float* __restrict__ Wq, const float* __restrict__ bq,
    const float* __restrict__ Wv, const float* __restrict__ bv,
    float* __restrict__ partQ) {
    const int lane = threadIdx.x;
    const int w = blockIdx.z;                    // output group 0..3 (9 outputs)
    const int row = blockIdx.x * 64 + lane;
    const int ec = blockIdx.y;

    const float4* xp = (const float4*)(xe + (size_t)row * E_DIM + ec * ECOLS);

    float acc[9]; const float4* wp[9]; int col[9]; float bias[9]; bool live[9];
#pragma unroll
    for (int k = 0; k < 9; ++k) {
        int o = w * 9 + k;
        const float* base; float b; int c; bool lv = true;
        if (o < 11)      { base = Wk + (size_t)o * E_DIM;      b = bk[o];    c = o; }
        else if (o < 22) { base = Wq + (size_t)(o-11) * E_DIM; b = bq[o-11]; c = o + 1; }
        else if (o < 33) { base = Wv + (size_t)(o-22) * E_DIM; b = bv[o-22]; c = o + 2; }
        else             { base = Wk; b = 0.f; c = 0; lv = false; }
        wp[k] = (const float4*)(base + ec * ECOLS);
        acc[k] = 0.f; col[k] = c; bias[k] = b; live[k] = lv;
    }

#pragma unroll 4
    for (int c4 = 0; c4 < ECOLS / 4; ++c4) {
        float4 xv = xp[c4];
#pragma unroll
        for (int k = 0; k < 9; ++k) {
            float4 wv = wp[k][c4];
            acc[k] += (xv.x * wv.x + xv.y * wv.y) + (xv.z * wv.z + xv.w * wv.w);
        }
    }

    float* dst = partQ + ((size_t)ec * T_SEQ + row) * QS;
#pragma unroll
    for (int k = 0; k < 9; ++k)
        if (live[k]) dst[col[k]] = acc[k] + (ec == 0 ? bias[k] : 0.f);
}

// ---------------------------------------------------------------------------
// K2: reduce the NEC qkv partial chunks into the dense qkvF buffer.
// ---------------------------------------------------------------------------
__global__ __launch_bounds__(256) void reduceQ(const float* __restrict__ partQ,
                                               float* __restrict__ qkvF) {
    const size_t idx = (size_t)blockIdx.x * 256 + threadIdx.x;   // float4 index
    const float4* p = (const float4*)partQ;
    const size_t cs = (size_t)T_SEQ * (QS / 4);
    float4 a = p[idx], b = p[idx + cs], c = p[idx + 2 * cs], d = p[idx + 3 * cs];
    float4 s;
    s.x = (a.x + b.x) + (c.x + d.x);
    s.y = (a.y + b.y) + (c.y + d.y);
    s.z = (a.z + b.z) + (c.z + d.z);
    s.w = (a.w + b.w) + (c.w + d.w);
    ((float4*)qkvF)[idx] = s;
}

// ---------------------------------------------------------------------------
// K3: causal attention. Block = 256 thr = 4 waves, owns RPB=512 rows (2/thread).
// KV chunk of JC=128 rows staged in LDS once (no loop barrier); inner loop is
// pure LDS-broadcast reads + VALU. Partials stored with plain coalesced float4
// stores into part[jc][row][12] (no atomics). Diagonal blocks take MASK path.
// ---------------------------------------------------------------------------
template <bool MASK>
__device__ __forceinline__ void attn_body(const float* __restrict__ qkvF,
                                          float* __restrict__ part,
                                          const float* kv, int row0, int j0, int jc) {
    const int r0 = row0 + threadIdx.x * 2;
    const float4* qp0 = (const float4*)(qkvF + (size_t)r0 * QS + 12);
    const float4* qp1 = (const float4*)(qkvF + (size_t)(r0 + 1) * QS + 12);
    const float4 qa0 = qp0[0], qa1 = qp0[1], qa2 = qp0[2];
    const float4 qb0 = qp1[0], qb1 = qp1[1], qb2 = qp1[2];

    float oa[12], ob[12];
#pragma unroll
    for (int d = 0; d < 12; ++d) { oa[d] = 0.f; ob[d] = 0.f; }

    const float* kp = kv;
#pragma unroll 2
    for (int jj = 0; jj < JC; ++jj) {
        float4 k0 = *(const float4*)(kp);
        float4 k1 = *(const float4*)(kp + 4);
        float4 k2 = *(const float4*)(kp + 8);
        float4 v0 = *(const float4*)(kp + 24);
        float4 v1 = *(const float4*)(kp + 28);
        float4 v2 = *(const float4*)(kp + 32);
        kp += QS;
        float sa = ((qa0.x * k0.x + qa0.y * k0.y) + (qa0.z * k0.z + qa0.w * k0.w))
                 + ((qa1.x * k1.x + qa1.y * k1.y) + (qa1.z * k1.z + qa1.w * k1.w))
                 + ((qa2.x * k2.x + qa2.y * k2.y) + qa2.z * k2.z);
        float sb = ((qb0.x * k0.x + qb0.y * k0.y) + (qb0.z * k0.z + qb0.w * k0.w))
                 + ((qb1.x * k1.x + qb1.y * k1.y) + (qb1.z * k1.z + qb1.w * k1.w))
                 + ((qb2.x * k2.x + qb2.y * k2.y) + qb2.z * k2.z);
        float pa = __expf(sa), pb = __expf(sb);
        if (MASK) {
            const int j = j0 + jj;
            pa = (j <= r0)     ? pa : 0.f;
            pb = (j <= r0 + 1) ? pb : 0.f;
        }
        oa[11] += pa; ob[11] += pb;
        oa[0] += pa * v0.x; oa[1] += pa * v0.y; oa[2]  += pa * v0.z; oa[3] += pa * v0.w;
        oa[4] += pa * v1.x; oa[5] += pa * v1.y; oa[6]  += pa * v1.z; oa[7] += pa * v1.w;
        oa[8] += pa * v2.x; oa[9] += pa * v2.y; oa[10] += pa * v2.z;
        ob[0] += pb * v0.x; ob[1] += pb * v0.y; ob[2]  += pb * v0.z; ob[3] += pb * v0.w;
        ob[4] += pb * v1.x; ob[5] += pb * v1.y; ob[6]  += pb * v1.z; ob[7] += pb * v1.w;
        ob[8] += pb * v2.x; ob[9] += pb * v2.y; ob[10] += pb * v2.z;
    }

    float* dst = part + ((size_t)jc * T_SEQ + r0) * 12;
    float4 t;
    t.x = oa[0];  t.y = oa[1];  t.z = oa[2];  t.w = oa[3];  *(float4*)(dst + 0)  = t;
    t.x = oa[4];  t.y = oa[5];  t.z = oa[6];  t.w = oa[7];  *(float4*)(dst + 4)  = t;
    t.x = oa[8];  t.y = oa[9];  t.z = oa[10]; t.w = oa[11]; *(float4*)(dst + 8)  = t;
    t.x = ob[0];  t.y = ob[1];  t.z = ob[2];  t.w = ob[3];  *(float4*)(dst + 12) = t;
    t.x = ob[4];  t.y = ob[5];  t.z = ob[6];  t.w = ob[7];  *(float4*)(dst + 16) = t;
    t.x = ob[8];  t.y = ob[9];  t.z = ob[10]; t.w = ob[11]; *(float4*)(dst + 20) = t;
}

__global__ __launch_bounds__(256) void attn(const float* __restrict__ qkvF,
                                            float* __restrict__ part) {
    const int ib = blockIdx.x, jc = blockIdx.y;
    const int row0 = ib * RPB;
    const int j0 = jc * JC;
    if (j0 > row0 + RPB - 1) return;              // chunk entirely above diagonal

    __shared__ float kv[JC * QS];
    {
        const float4* src = (const float4*)(qkvF + (size_t)j0 * QS);
        float4* dst = (float4*)kv;
        for (int idx = threadIdx.x; idx < JC * (QS / 4); idx += 256)
            dst[idx] = src[idx];
    }
    __syncthreads();

    if (j0 + JC - 1 <= row0)
        attn_body<false>(qkvF, part, kv, row0, j0, jc);
    else
        attn_body<true>(qkvF, part, kv, row0, j0, jc);
}

// ---------------------------------------------------------------------------
// K4: fused partial-reduce + normalize + output GEMM + bias.
// Block owns TR=16 rows. Phase A: 192 threads, thread=(row,d), fully coalesced
// (consecutive tid = consecutive floats). Phase B: thread owns 4 output cols.
// ---------------------------------------------------------------------------
__global__ __launch_bounds__(256) void pass2(const float* __restrict__ part,
                                             const float* __restrict__ Wf,
                                             const float* __restrict__ bf,
                                             float* __restrict__ out) {
    const int t0 = blockIdx.x * TR;
    __shared__ float res[TR][12];
    const int cnt = t0 / JC + 1;                  // uniform per block (16 | 128)
    if (threadIdx.x < TR * 12) {
        const float* p = part + (size_t)t0 * 12 + threadIdx.x;
        float v = 0.f;
        for (int c = 0; c < cnt; ++c) v += p[(size_t)c * T_SEQ * 12];
        const int d = threadIdx.x % 12;
        res[threadIdx.x / 12][d] = (d == 11) ? (1.f / v) : v;
    }
    __syncthreads();

    const int e0 = threadIdx.x * 4;
    float wfv[4][11];
#pragma unroll
    for (int ee = 0; ee < 4; ++ee)
#pragma unroll
        for (int d = 0; d < 11; ++d)
            wfv[ee][d] = Wf[(size_t)(e0 + ee) * 11 + d];
    const float4 bv = *(const float4*)(bf + e0);

    for (int r = 0; r < TR; ++r) {
        float rr[12];
#pragma unroll
        for (int d = 0; d < 12; ++d) rr[d] = res[r][d];
        float a0 = 0.f, a1 = 0.f, a2 = 0.f, a3 = 0.f;
#pragma unroll
        for (int d = 0; d < 11; ++d) {
            a0 += rr[d] * wfv[0][d]; a1 += rr[d] * wfv[1][d];
            a2 += rr[d] * wfv[2][d]; a3 += rr[d] * wfv[3][d];
        }
        float4 ov;
        ov.x = a0 * rr[11] + bv.x; ov.y = a1 * rr[11] + bv.y;
        ov.z = a2 * rr[11] + bv.z; ov.w = a3 * rr[11] + bv.w;
        *(float4*)(out + (size_t)(t0 + r) * E_DIM + e0) = ov;
    }
}

// ---------------------------------------------------------------------------
extern "C" void kernel_launch(void* const* d_in, const int* in_sizes, int n_in,
                              void* d_out, int out_size, void* d_ws, size_t ws_size,
                              hipStream_t stream) {
    const float* xe = (const float*)d_in[1];
    const float* Wk = (const float*)d_in[2];
    const float* bk = (const float*)d_in[3];
    const float* Wq = (const float*)d_in[4];
    const float* bq = (const float*)d_in[5];
    const float* Wv = (const float*)d_in[6];
    const float* bv = (const float*)d_in[7];
    const float* Wf = (const float*)d_in[8];
    const float* bf = (const float*)d_in[9];
    float* out = (float*)d_out;

    float* partQ = (float*)d_ws;                              // [NEC][T][QS]
    float* qkvF  = partQ + (size_t)NEC * T_SEQ * QS;          // [T][QS]
    float* part  = qkvF + (size_t)T_SEQ * QS;                 // [NJC][T][12]

    qkv_proj<<<dim3(T_SEQ / 64, NEC, 4), 64, 0, stream>>>(xe, Wk, bk, Wq, bq, Wv, bv, partQ);
    reduceQ<<<(T_SEQ * (QS / 4)) / 256, 256, 0, stream>>>(partQ, qkvF);
    attn<<<dim3(NIB, NJC), 256, 0, stream>>>(qkvF, part);
    pass2<<<T_SEQ / TR, 256, 0, stream>>>(part, Wf, bf, out);
}

// Round 3
// 219.682 us; speedup vs baseline: 1.5889x; 1.0453x over previous
//
#include <hip/hip_runtime.h>

#define T_SEQ 8192
#define E_DIM 1024
#define QS 36              // padded qkv row: [k 0..10][pad][q 12..22][pad][v 24..34][pad]
#define NEC 4              // E-chunks in qkv projection
#define ECOLS 256          // cols per qkv block
#define KC 128             // cols per LDS sub-chunk
#define XP 129             // padded LDS row stride (odd -> conflict-free lane=row reads)
#define RB 64              // qkv rows per block
#define JCH 128            // attn j-chunk rows
#define NJC (T_SEQ / JCH)  // 64
#define RPB 256            // attn rows per block (1 row/thread)
#define TR 16              // pass2 rows per block

__device__ __forceinline__ float2 pkfma(float2 a, float2 b, float2 c) {
    return make_float2(fmaf(a.x, b.x, c.x), fmaf(a.y, b.y, c.y));
}
__device__ __forceinline__ float2 f2(float x, float y) { return make_float2(x, y); }

// ws layout (floats):
//   partQ [NEC][T][QS] = 4.72 MB ; qkvF [T][QS] = 1.18 MB
//   part  [NJC][T][12] = 25.2 MB ; Wfp [E][12] = 48 KB

// ---------------------------------------------------------------------------
// K0: pad Wf [E][11] -> [E][12] for coalesced float4 loads in pass2
// ---------------------------------------------------------------------------
__global__ __launch_bounds__(256) void prep_wf(const float* __restrict__ Wf,
                                               float* __restrict__ Wfp) {
    int id = blockIdx.x * 256 + threadIdx.x;
    if (id >= E_DIM * 12) return;
    int e = id / 12, d = id % 12;
    Wfp[id] = (d < 11) ? Wf[(size_t)e * 11 + d] : 0.f;
}

// ---------------------------------------------------------------------------
// K1: qkv projection. Block = 256 thr = 4 waves; 64 rows x 256-col chunk.
// xe tile staged in LDS via coalesced float4 global loads (stride-129 pad ->
// 2-way-free compute reads, lane = row). Wave w owns 9 outputs; weight
// addresses wave-uniform (readfirstlane) -> scalar loads. Packed fp32 FMA.
// Dummy outputs (33..35) write 0 to pad cols 11/23/35 so qkvF pads are clean.
// ---------------------------------------------------------------------------
__global__ __launch_bounds__(256) void qkv_proj(
    const float* __restrict__ xe,
    const float* __restrict__ Wk, const float* __restrict__ bk,
    const float* __restrict__ Wq, const float* __restrict__ bq,
    const float* __restrict__ Wv, const float* __restrict__ bv,
    float* __restrict__ partQ) {
    const int row0 = blockIdx.x * RB;
    const int ec = blockIdx.y;
    const int lane = threadIdx.x & 63;
    const int wg = __builtin_amdgcn_readfirstlane(threadIdx.x >> 6);

    __shared__ float xt[RB * XP];

    const float* wrow[9]; int col[9]; float bias[9]; bool live[9];
#pragma unroll
    for (int k = 0; k < 9; ++k) {
        int o = wg * 9 + k;
        const float* base; float b = 0.f; int c; bool lv = true;
        if (o < 11)      { base = Wk + (size_t)o * E_DIM;        b = bk[o];      c = o; }
        else if (o < 22) { base = Wq + (size_t)(o - 11) * E_DIM; b = bq[o - 11]; c = o + 1; }
        else if (o < 33) { base = Wv + (size_t)(o - 22) * E_DIM; b = bv[o - 22]; c = o + 2; }
        else             { base = Wk; c = (o == 33) ? 11 : (o == 34) ? 23 : 35; lv = false; }
        wrow[k] = base; col[k] = c; bias[k] = b; live[k] = lv;
    }

    float2 acc2[9];
#pragma unroll
    for (int k = 0; k < 9; ++k) acc2[k] = make_float2(0.f, 0.f);

    for (int sub = 0; sub < ECOLS / KC; ++sub) {
        const int cbase = ec * ECOLS + sub * KC;
        if (sub) __syncthreads();
        for (int idx = threadIdx.x; idx < RB * (KC / 4); idx += 256) {
            int r = idx >> 5, c4 = idx & 31;
            float4 v = *(const float4*)(xe + (size_t)(row0 + r) * E_DIM + cbase + c4 * 4);
            float* d = xt + r * XP + c4 * 4;
            d[0] = v.x; d[1] = v.y; d[2] = v.z; d[3] = v.w;
        }
        __syncthreads();

        const float* xr = xt + lane * XP;
#pragma unroll 4
        for (int c = 0; c < KC; c += 4) {
            float2 xa = f2(xr[c], xr[c + 1]);
            float2 xb = f2(xr[c + 2], xr[c + 3]);
#pragma unroll
            for (int k = 0; k < 9; ++k) {
                float4 wv = *(const float4*)(wrow[k] + cbase + c);
                acc2[k] = pkfma(xa, f2(wv.x, wv.y), acc2[k]);
                acc2[k] = pkfma(xb, f2(wv.z, wv.w), acc2[k]);
            }
        }
    }

    float* dst = partQ + ((size_t)ec * T_SEQ + row0 + lane) * QS;
#pragma unroll
    for (int k = 0; k < 9; ++k) {
        float v = acc2[k].x + acc2[k].y + (ec == 0 ? bias[k] : 0.f);
        dst[col[k]] = live[k] ? v : 0.f;
    }
}

// ---------------------------------------------------------------------------
// K2: reduce NEC qkv partial chunks into dense qkvF.
// ---------------------------------------------------------------------------
__global__ __launch_bounds__(256) void reduceQ(const float* __restrict__ partQ,
                                               float* __restrict__ qkvF) {
    const size_t idx = (size_t)blockIdx.x * 256 + threadIdx.x;
    const float4* p = (const float4*)partQ;
    const size_t cs = (size_t)T_SEQ * (QS / 4);
    float4 a = p[idx], b = p[idx + cs], c = p[idx + 2 * cs], d = p[idx + 3 * cs];
    float4 s;
    s.x = (a.x + b.x) + (c.x + d.x);
    s.y = (a.y + b.y) + (c.y + d.y);
    s.z = (a.z + b.z) + (c.z + d.z);
    s.w = (a.w + b.w) + (c.w + d.w);
    ((float4*)qkvF)[idx] = s;
}

// ---------------------------------------------------------------------------
// K3: causal attention. Block = 256 thr = 4 waves, 1 row/thread (RPB=256).
// 1056 active blocks (~4 waves/SIMD). KV chunk (128 rows) in LDS; inner loop
// is LDS same-address broadcast reads + packed fp32 FMA. Plain coalesced
// partial stores to part[jc][row][12].
// ---------------------------------------------------------------------------
template <bool MASK>
__device__ __forceinline__ void attn_body(const float* __restrict__ qkvF,
                                          float* __restrict__ part,
                                          const float* kv, int row0, int j0, int jc) {
    const int i = row0 + threadIdx.x;
    const float* qp = qkvF + (size_t)i * QS + 12;
    const float2 q01 = *(const float2*)(qp);
    const float2 q23 = *(const float2*)(qp + 2);
    const float2 q45 = *(const float2*)(qp + 4);
    const float2 q67 = *(const float2*)(qp + 6);
    const float2 q89 = *(const float2*)(qp + 8);
    const float  q10 = qp[10];

    float2 o01 = f2(0.f, 0.f), o23 = o01, o45 = o01, o67 = o01, o89 = o01;
    float o10 = 0.f, l = 0.f;

    const float* kp = kv;
#pragma unroll 2
    for (int jj = 0; jj < JCH; ++jj) {
        const float4 kA = *(const float4*)(kp);
        const float4 kB = *(const float4*)(kp + 4);
        const float4 kC = *(const float4*)(kp + 8);
        const float4 vA = *(const float4*)(kp + 24);
        const float4 vB = *(const float4*)(kp + 28);
        const float4 vC = *(const float4*)(kp + 32);
        kp += QS;

        float2 s2 = pkfma(q01, f2(kA.x, kA.y),
                    pkfma(q23, f2(kA.z, kA.w),
                    pkfma(q45, f2(kB.x, kB.y),
                    pkfma(q67, f2(kB.z, kB.w),
                    pkfma(q89, f2(kC.x, kC.y), f2(0.f, 0.f))))));
        float s = s2.x + s2.y + q10 * kC.z;
        float p = __expf(s);
        if (MASK) p = (j0 + jj <= i) ? p : 0.f;
        l += p;
        float2 p2 = f2(p, p);
        o01 = pkfma(p2, f2(vA.x, vA.y), o01);
        o23 = pkfma(p2, f2(vA.z, vA.w), o23);
        o45 = pkfma(p2, f2(vB.x, vB.y), o45);
        o67 = pkfma(p2, f2(vB.z, vB.w), o67);
        o89 = pkfma(p2, f2(vC.x, vC.y), o89);
        o10 += p * vC.z;
    }

    float* dst = part + ((size_t)jc * T_SEQ + i) * 12;
    float4 t;
    t.x = o01.x; t.y = o01.y; t.z = o23.x; t.w = o23.y; *(float4*)(dst + 0) = t;
    t.x = o45.x; t.y = o45.y; t.z = o67.x; t.w = o67.y; *(float4*)(dst + 4) = t;
    t.x = o89.x; t.y = o89.y; t.z = o10;   t.w = l;     *(float4*)(dst + 8) = t;
}

__global__ __launch_bounds__(256) void attn(const float* __restrict__ qkvF,
                                            float* __restrict__ part) {
    const int ib = blockIdx.x, jc = blockIdx.y;
    if (jc > 2 * ib + 1) return;              // entirely above diagonal
    const int row0 = ib * RPB, j0 = jc * JCH;

    __shared__ float kv[JCH * QS];
    {
        const float4* src = (const float4*)(qkvF + (size_t)j0 * QS);
        float4* dst = (float4*)kv;
        for (int idx = threadIdx.x; idx < JCH * (QS / 4); idx += 256)
            dst[idx] = src[idx];
    }
    __syncthreads();

    if (jc <= 2 * ib - 1)
        attn_body<false>(qkvF, part, kv, row0, j0, jc);
    else
        attn_body<true>(qkvF, part, kv, row0, j0, jc);
}

// ---------------------------------------------------------------------------
// K4: fused partial-reduce + normalize + output GEMM + bias.
// Phase A: 192 thr coalesced chunk reduction into res[TR][12].
// Phase B: thread owns 4 output cols; Wfp rows loaded as 3 coalesced float4.
// ---------------------------------------------------------------------------
__global__ __launch_bounds__(256) void pass2(const float* __restrict__ part,
                                             const float* __restrict__ Wfp,
                                             const float* __restrict__ bf,
                                             float* __restrict__ out) {
    const int t0 = blockIdx.x * TR;
    __shared__ float res[TR][12];
    const int cnt = t0 / JCH + 1;             // uniform per block
    if (threadIdx.x < TR * 12) {
        const float* p = part + (size_t)t0 * 12 + threadIdx.x;
        float v = 0.f;
        for (int c = 0; c < cnt; ++c) v += p[(size_t)c * T_SEQ * 12];
        const int d = threadIdx.x % 12;
        res[threadIdx.x / 12][d] = (d == 11) ? (1.f / v) : v;
    }
    __syncthreads();

    const int e0 = threadIdx.x * 4;
    float4 wf[4][3];
#pragma unroll
    for (int ee = 0; ee < 4; ++ee) {
        const float4* wp = (const float4*)(Wfp + (size_t)(e0 + ee) * 12);
        wf[ee][0] = wp[0]; wf[ee][1] = wp[1]; wf[ee][2] = wp[2];
    }
    const float4 bv = *(const float4*)(bf + e0);

    for (int r = 0; r < TR; ++r) {
        float rr[12];
#pragma unroll
        for (int d = 0; d < 12; ++d) rr[d] = res[r][d];
        float2 a0 = f2(0.f, 0.f), a1 = a0, a2 = a0, a3 = a0;
#pragma unroll
        for (int d = 0; d < 10; d += 2) {
            float2 rv = f2(rr[d], rr[d + 1]);
            a0 = pkfma(rv, f2(((const float*)&wf[0][0])[d], ((const float*)&wf[0][0])[d + 1]), a0);
            a1 = pkfma(rv, f2(((const float*)&wf[1][0])[d], ((const float*)&wf[1][0])[d + 1]), a1);
            a2 = pkfma(rv, f2(((const float*)&wf[2][0])[d], ((const float*)&wf[2][0])[d + 1]), a2);
            a3 = pkfma(rv, f2(((const float*)&wf[3][0])[d], ((const float*)&wf[3][0])[d + 1]), a3);
        }
        const float rl = rr[11];
        float4 ov;
        ov.x = (a0.x + a0.y + rr[10] * wf[0][2].z) * rl + bv.x;
        ov.y = (a1.x + a1.y + rr[10] * wf[1][2].z) * rl + bv.y;
        ov.z = (a2.x + a2.y + rr[10] * wf[2][2].z) * rl + bv.z;
        ov.w = (a3.x + a3.y + rr[10] * wf[3][2].z) * rl + bv.w;
        *(float4*)(out + (size_t)(t0 + r) * E_DIM + e0) = ov;
    }
}

// ---------------------------------------------------------------------------
extern "C" void kernel_launch(void* const* d_in, const int* in_sizes, int n_in,
                              void* d_out, int out_size, void* d_ws, size_t ws_size,
                              hipStream_t stream) {
    const float* xe = (const float*)d_in[1];
    const float* Wk = (const float*)d_in[2];
    const float* bk = (const float*)d_in[3];
    const float* Wq = (const float*)d_in[4];
    const float* bq = (const float*)d_in[5];
    const float* Wv = (const float*)d_in[6];
    const float* bv = (const float*)d_in[7];
    const float* Wf = (const float*)d_in[8];
    const float* bf = (const float*)d_in[9];
    float* out = (float*)d_out;

    float* partQ = (float*)d_ws;                              // [NEC][T][QS]
    float* qkvF  = partQ + (size_t)NEC * T_SEQ * QS;          // [T][QS]
    float* part  = qkvF + (size_t)T_SEQ * QS;                 // [NJC][T][12]
    float* wfp   = part + (size_t)NJC * T_SEQ * 12;           // [E][12]

    prep_wf<<<(E_DIM * 12 + 255) / 256, 256, 0, stream>>>(Wf, wfp);
    qkv_proj<<<dim3(T_SEQ / RB, NEC), 256, 0, stream>>>(xe, Wk, bk, Wq, bq, Wv, bv, partQ);
    reduceQ<<<(T_SEQ * (QS / 4)) / 256, 256, 0, stream>>>(partQ, qkvF);
    attn<<<dim3(T_SEQ / RPB, NJC), 256, 0, stream>>>(qkvF, part);
    pass2<<<T_SEQ / TR, 256, 0, stream>>>(part, wfp, bf, out);
}

// Round 5
// 193.314 us; speedup vs baseline: 1.8057x; 1.1364x over previous
//
#include <hip/hip_runtime.h>

#define T_SEQ 8192
#define E_DIM 1024
#define QS 36              // padded qkv row: [k 0..10][pad][q 12..22][pad][v 24..34][pad]
#define NEC 4              // E-chunks in qkv projection
#define ECOLS 256          // cols per qkv block
#define KC 64              // cols per LDS sub-chunk
#define C2N 32             // KC/2 column pairs
#define XST 65             // float2 row stride in xP (odd -> conflict-benign LDS access)
#define RB 64              // qkv rows per block
#define JCH 128            // attn j-chunk rows
#define NJC (T_SEQ / JCH)  // 64
#define RPB 512            // attn rows per block (2 rows/thread)
#define NIB (T_SEQ / RPB)  // 16
#define TR 16              // pass2 rows per block

__device__ __forceinline__ float2 pkfma(float2 a, float2 b, float2 c) {
    return make_float2(fmaf(a.x, b.x, c.x), fmaf(a.y, b.y, c.y));
}
__device__ __forceinline__ float2 f2(float x, float y) { return make_float2(x, y); }

// ws floats: partQ[NEC][T][QS] 4.72MB ; qkvF[T][QS] 1.18MB ; part[NJC][T][12] 25.2MB ; Wfp[E][12] 48KB

// ---------------------------------------------------------------------------
// K0: pad Wf [E][11] -> [E][12] for coalesced float4 loads in pass2
// ---------------------------------------------------------------------------
__global__ __launch_bounds__(256) void prep_wf(const float* __restrict__ Wf,
                                               float* __restrict__ Wfp) {
    int id = blockIdx.x * 256 + threadIdx.x;
    if (id >= E_DIM * 12) return;
    int e = id / 12, d = id % 12;
    Wfp[id] = (d < 11) ? Wf[(size_t)e * 11 + d] : 0.f;
}

// ---------------------------------------------------------------------------
// K1: qkv projection. Block = 256 thr; 64 rows x 256 cols (NEC=4 col-chunks).
// xe staged in LDS column-pair layout xP[c2][row] (float2, stride 65): compute
// reads are ds_read_b64, one per 9 packed FMAs. Weights are wave-uniform
// float2 reads -> scalar-pipe s_load (no vector-mem in the compute loop).
// Staging prefetched one sub-chunk ahead: 4 float4/thread (FULL 64x64 tile —
// R4 bug was 2/thread = half tile, leaving xP rows 16..31 poisoned).
// ---------------------------------------------------------------------------
__global__ __launch_bounds__(256) void qkv_proj(
    const float* __restrict__ xe,
    const float* __restrict__ Wk, const float* __restrict__ bk,
    const float* __restrict__ Wq, const float* __restrict__ bq,
    const float* __restrict__ Wv, const float* __restrict__ bv,
    float* __restrict__ partQ) {
    const int row0 = blockIdx.x * RB;
    const int ec = blockIdx.y;
    const int lane = threadIdx.x & 63;
    const int wg = __builtin_amdgcn_readfirstlane(threadIdx.x >> 6);

    __shared__ float2 xP[C2N * XST];

    const float* wrow[9]; int col[9]; float bias[9]; bool live[9];
#pragma unroll
    for (int k = 0; k < 9; ++k) {
        int o = wg * 9 + k;
        const float* base; float b = 0.f; int c; bool lv = true;
        if (o < 11)      { base = Wk + (size_t)o * E_DIM;        b = bk[o];      c = o; }
        else if (o < 22) { base = Wq + (size_t)(o - 11) * E_DIM; b = bq[o - 11]; c = o + 1; }
        else if (o < 33) { base = Wv + (size_t)(o - 22) * E_DIM; b = bv[o - 22]; c = o + 2; }
        else             { base = Wk; c = (o == 33) ? 11 : (o == 34) ? 23 : 35; lv = false; }
        wrow[k] = base; col[k] = c; bias[k] = b; live[k] = lv;
    }

    float2 acc[9];
#pragma unroll
    for (int k = 0; k < 9; ++k) acc[k] = f2(0.f, 0.f);

    float4 st[4];
    // staging map: idx -> r = idx>>4 (0..63), c4 = idx&15 (16 float4 per 64-col row)
#define STAGE_LOAD(sub)                                                         \
    {                                                                           \
        const int cb = ec * ECOLS + (sub) * KC;                                 \
        _Pragma("unroll")                                                       \
        for (int t = 0; t < 4; ++t) {                                           \
            int idx = threadIdx.x + t * 256;                                    \
            int r = idx >> 4, c4 = idx & 15;                                    \
            st[t] = *(const float4*)(xe + (size_t)(row0 + r) * E_DIM + cb + c4 * 4); \
        }                                                                       \
    }

    STAGE_LOAD(0);
    for (int sub = 0; sub < ECOLS / KC; ++sub) {
        if (sub) __syncthreads();                 // WAR: prev compute done
#pragma unroll
        for (int t = 0; t < 4; ++t) {
            int idx = threadIdx.x + t * 256;
            int r = idx >> 4, c4 = idx & 15;
            float2* d = &xP[(size_t)(c4 * 2) * XST + r];
            d[0]   = f2(st[t].x, st[t].y);
            d[XST] = f2(st[t].z, st[t].w);
        }
        if (sub + 1 < ECOLS / KC) STAGE_LOAD(sub + 1);
        __syncthreads();

        const int cbase = ec * ECOLS + sub * KC;
#pragma unroll 4
        for (int c2 = 0; c2 < C2N; ++c2) {
            float2 xv = xP[c2 * XST + lane];
            const int c = cbase + 2 * c2;
#pragma unroll
            for (int k = 0; k < 9; ++k) {
                const float2 wv = *(const float2*)(wrow[k] + c);
                acc[k] = pkfma(xv, wv, acc[k]);
            }
        }
    }
#undef STAGE_LOAD

    float* dst = partQ + ((size_t)ec * T_SEQ + row0 + lane) * QS;
#pragma unroll
    for (int k = 0; k < 9; ++k) {
        float v = acc[k].x + acc[k].y + (ec == 0 ? bias[k] : 0.f);
        dst[col[k]] = live[k] ? v : 0.f;
    }
}

// ---------------------------------------------------------------------------
// K2: reduce NEC qkv partial chunks into dense qkvF.
// ---------------------------------------------------------------------------
__global__ __launch_bounds__(256) void reduceQ(const float* __restrict__ partQ,
                                               float* __restrict__ qkvF) {
    const size_t idx = (size_t)blockIdx.x * 256 + threadIdx.x;
    const float4* p = (const float4*)partQ;
    const size_t cs = (size_t)T_SEQ * (QS / 4);
    float4 a = p[idx], b = p[idx + cs], c = p[idx + 2 * cs], d = p[idx + 3 * cs];
    float4 s;
    s.x = (a.x + b.x) + (c.x + d.x);
    s.y = (a.y + b.y) + (c.y + d.y);
    s.z = (a.z + b.z) + (c.z + d.z);
    s.w = (a.w + b.w) + (c.w + d.w);
    ((float4*)qkvF)[idx] = s;
}

// ---------------------------------------------------------------------------
// K3: causal attention. Block = 256 thr = 4 waves, RPB=512 rows (2/thread),
// 544 uniform-work blocks. KV chunk in LDS; inner loop uses explicit register
// rotation (prefetch kv[jj+1] while computing kv[jj]) so the 6 ds_read_b128
// always overlap compute. q pre-scaled by log2e -> exp2f. launch_bounds(,4)
// caps VGPRs at 128 for 16 waves/CU.
// ---------------------------------------------------------------------------
#define LOG2E 1.4426950408889634f

template <bool MASK>
__device__ __forceinline__ void attn_body(const float* __restrict__ qkvF,
                                          float* __restrict__ part,
                                          const float* kv, int row0, int j0, int jc) {
    const int r0 = row0 + threadIdx.x * 2;
    const float* qp0 = qkvF + (size_t)r0 * QS + 12;
    const float* qp1 = qp0 + QS;
    float4 qa0 = *(const float4*)(qp0), qa1 = *(const float4*)(qp0 + 4), qa2 = *(const float4*)(qp0 + 8);
    float4 qb0 = *(const float4*)(qp1), qb1 = *(const float4*)(qp1 + 4), qb2 = *(const float4*)(qp1 + 8);
    qa0.x *= LOG2E; qa0.y *= LOG2E; qa0.z *= LOG2E; qa0.w *= LOG2E;
    qa1.x *= LOG2E; qa1.y *= LOG2E; qa1.z *= LOG2E; qa1.w *= LOG2E;
    qa2.x *= LOG2E; qa2.y *= LOG2E; qa2.z *= LOG2E;
    qb0.x *= LOG2E; qb0.y *= LOG2E; qb0.z *= LOG2E; qb0.w *= LOG2E;
    qb1.x *= LOG2E; qb1.y *= LOG2E; qb1.z *= LOG2E; qb1.w *= LOG2E;
    qb2.x *= LOG2E; qb2.y *= LOG2E; qb2.z *= LOG2E;

    float2 a01 = f2(0.f, 0.f), a23 = a01, a45 = a01, a67 = a01, a89 = a01, aXL = a01;
    float2 b01 = a01, b23 = a01, b45 = a01, b67 = a01, b89 = a01, bXL = a01;

    const float* kp = kv;
    float4 cK0 = *(const float4*)(kp),      cK1 = *(const float4*)(kp + 4),  cK2 = *(const float4*)(kp + 8);
    float4 cV0 = *(const float4*)(kp + 24), cV1 = *(const float4*)(kp + 28), cV2 = *(const float4*)(kp + 32);

#pragma unroll 2
    for (int jj = 0; jj < JCH; ++jj) {
        // unconditional prefetch (clamped on last iter -> valid LDS, value unused)
        const float* np = kp + ((jj + 1 < JCH) ? QS : 0);
        float4 nK0 = *(const float4*)(np);      float4 nK1 = *(const float4*)(np + 4);
        float4 nK2 = *(const float4*)(np + 8);
        float4 nV0 = *(const float4*)(np + 24); float4 nV1 = *(const float4*)(np + 28);
        float4 nV2 = *(const float4*)(np + 32);

        float2 sa = pkfma(f2(qa0.x, qa0.y), f2(cK0.x, cK0.y),
                    pkfma(f2(qa0.z, qa0.w), f2(cK0.z, cK0.w),
                    pkfma(f2(qa1.x, qa1.y), f2(cK1.x, cK1.y),
                    pkfma(f2(qa1.z, qa1.w), f2(cK1.z, cK1.w),
                    pkfma(f2(qa2.x, qa2.y), f2(cK2.x, cK2.y), f2(0.f, 0.f))))));
        float2 sb = pkfma(f2(qb0.x, qb0.y), f2(cK0.x, cK0.y),
                    pkfma(f2(qb0.z, qb0.w), f2(cK0.z, cK0.w),
                    pkfma(f2(qb1.x, qb1.y), f2(cK1.x, cK1.y),
                    pkfma(f2(qb1.z, qb1.w), f2(cK1.z, cK1.w),
                    pkfma(f2(qb2.x, qb2.y), f2(cK2.x, cK2.y), f2(0.f, 0.f))))));
        float pa = exp2f(sa.x + sa.y + qa2.z * cK2.z);
        float pb = exp2f(sb.x + sb.y + qb2.z * cK2.z);
        if (MASK) {
            pa = (j0 + jj <= r0)     ? pa : 0.f;
            pb = (j0 + jj <= r0 + 1) ? pb : 0.f;
        }
        float2 pa2 = f2(pa, pa), pb2 = f2(pb, pb);
        a01 = pkfma(pa2, f2(cV0.x, cV0.y), a01);
        a23 = pkfma(pa2, f2(cV0.z, cV0.w), a23);
        a45 = pkfma(pa2, f2(cV1.x, cV1.y), a45);
        a67 = pkfma(pa2, f2(cV1.z, cV1.w), a67);
        a89 = pkfma(pa2, f2(cV2.x, cV2.y), a89);
        aXL = pkfma(pa2, f2(cV2.z, 1.f),   aXL);
        b01 = pkfma(pb2, f2(cV0.x, cV0.y), b01);
        b23 = pkfma(pb2, f2(cV0.z, cV0.w), b23);
        b45 = pkfma(pb2, f2(cV1.x, cV1.y), b45);
        b67 = pkfma(pb2, f2(cV1.z, cV1.w), b67);
        b89 = pkfma(pb2, f2(cV2.x, cV2.y), b89);
        bXL = pkfma(pb2, f2(cV2.z, 1.f),   bXL);
        cK0 = nK0; cK1 = nK1; cK2 = nK2; cV0 = nV0; cV1 = nV1; cV2 = nV2;
        kp += QS;
    }

    float* dst = part + ((size_t)jc * T_SEQ + r0) * 12;
    float4 t;
    t.x = a01.x; t.y = a01.y; t.z = a23.x; t.w = a23.y; *(float4*)(dst + 0)  = t;
    t.x = a45.x; t.y = a45.y; t.z = a67.x; t.w = a67.y; *(float4*)(dst + 4)  = t;
    t.x = a89.x; t.y = a89.y; t.z = aXL.x; t.w = aXL.y; *(float4*)(dst + 8)  = t;
    t.x = b01.x; t.y = b01.y; t.z = b23.x; t.w = b23.y; *(float4*)(dst + 12) = t;
    t.x = b45.x; t.y = b45.y; t.z = b67.x; t.w = b67.y; *(float4*)(dst + 16) = t;
    t.x = b89.x; t.y = b89.y; t.z = bXL.x; t.w = bXL.y; *(float4*)(dst + 20) = t;
}

__global__ __launch_bounds__(256, 4) void attn(const float* __restrict__ qkvF,
                                               float* __restrict__ part) {
    const int ib = blockIdx.x, jc = blockIdx.y;
    if (jc > 4 * ib + 3) return;                  // entirely above diagonal
    const int row0 = ib * RPB, j0 = jc * JCH;

    __shared__ float kv[JCH * QS];
    {
        const float4* src = (const float4*)(qkvF + (size_t)j0 * QS);
        float4* dst = (float4*)kv;
        for (int idx = threadIdx.x; idx < JCH * (QS / 4); idx += 256)
            dst[idx] = src[idx];
    }
    __syncthreads();

    if (jc < 4 * ib)
        attn_body<false>(qkvF, part, kv, row0, j0, jc);
    else
        attn_body<true>(qkvF, part, kv, row0, j0, jc);
}

// ---------------------------------------------------------------------------
// K4: fused partial-reduce + normalize + output GEMM + bias.
// Phase A: 192 thr coalesced chunk reduction, 4-way unrolled (4 loads/batch).
// Phase B: thread owns 4 output cols; Wfp rows as 3 coalesced float4.
// ---------------------------------------------------------------------------
__global__ __launch_bounds__(256) void pass2(const float* __restrict__ part,
                                             const float* __restrict__ Wfp,
                                             const float* __restrict__ bf,
                                             float* __restrict__ out) {
    const int t0 = blockIdx.x * TR;
    __shared__ float res[TR][12];
    const int cnt = t0 / JCH + 1;             // uniform per block
    if (threadIdx.x < TR * 12) {
        const float* p = part + (size_t)t0 * 12 + threadIdx.x;
        const size_t S = (size_t)T_SEQ * 12;
        float v0 = 0.f, v1 = 0.f, v2 = 0.f, v3 = 0.f;
        int c = 0;
        for (; c + 4 <= cnt; c += 4) {
            v0 += p[(size_t)c * S];       v1 += p[(size_t)(c + 1) * S];
            v2 += p[(size_t)(c + 2) * S]; v3 += p[(size_t)(c + 3) * S];
        }
        for (; c < cnt; ++c) v0 += p[(size_t)c * S];
        float v = (v0 + v1) + (v2 + v3);
        const int d = threadIdx.x % 12;
        res[threadIdx.x / 12][d] = (d == 11) ? (1.f / v) : v;
    }
    __syncthreads();

    const int e0 = threadIdx.x * 4;
    float4 wf[4][3];
#pragma unroll
    for (int ee = 0; ee < 4; ++ee) {
        const float4* wp = (const float4*)(Wfp + (size_t)(e0 + ee) * 12);
        wf[ee][0] = wp[0]; wf[ee][1] = wp[1]; wf[ee][2] = wp[2];
    }
    const float4 bv = *(const float4*)(bf + e0);

    for (int r = 0; r < TR; ++r) {
        float rr[12];
#pragma unroll
        for (int d = 0; d < 12; ++d) rr[d] = res[r][d];
        float2 a0 = f2(0.f, 0.f), a1 = a0, a2 = a0, a3 = a0;
#pragma unroll
        for (int d = 0; d < 10; d += 2) {
            float2 rv = f2(rr[d], rr[d + 1]);
            a0 = pkfma(rv, f2(((const float*)&wf[0][0])[d], ((const float*)&wf[0][0])[d + 1]), a0);
            a1 = pkfma(rv, f2(((const float*)&wf[1][0])[d], ((const float*)&wf[1][0])[d + 1]), a1);
            a2 = pkfma(rv, f2(((const float*)&wf[2][0])[d], ((const float*)&wf[2][0])[d + 1]), a2);
            a3 = pkfma(rv, f2(((const float*)&wf[3][0])[d], ((const float*)&wf[3][0])[d + 1]), a3);
        }
        const float rl = rr[11];
        float4 ov;
        ov.x = (a0.x + a0.y + rr[10] * wf[0][2].z) * rl + bv.x;
        ov.y = (a1.x + a1.y + rr[10] * wf[1][2].z) * rl + bv.y;
        ov.z = (a2.x + a2.y + rr[10] * wf[2][2].z) * rl + bv.z;
        ov.w = (a3.x + a3.y + rr[10] * wf[3][2].z) * rl + bv.w;
        *(float4*)(out + (size_t)(t0 + r) * E_DIM + e0) = ov;
    }
}

// ---------------------------------------------------------------------------
extern "C" void kernel_launch(void* const* d_in, const int* in_sizes, int n_in,
                              void* d_out, int out_size, void* d_ws, size_t ws_size,
                              hipStream_t stream) {
    const float* xe = (const float*)d_in[1];
    const float* Wk = (const float*)d_in[2];
    const float* bk = (const float*)d_in[3];
    const float* Wq = (const float*)d_in[4];
    const float* bq = (const float*)d_in[5];
    const float* Wv = (const float*)d_in[6];
    const float* bv = (const float*)d_in[7];
    const float* Wf = (const float*)d_in[8];
    const float* bf = (const float*)d_in[9];
    float* out = (float*)d_out;

    float* partQ = (float*)d_ws;                              // [NEC][T][QS]
    float* qkvF  = partQ + (size_t)NEC * T_SEQ * QS;          // [T][QS]
    float* part  = qkvF + (size_t)T_SEQ * QS;                 // [NJC][T][12]
    float* wfp   = part + (size_t)NJC * T_SEQ * 12;           // [E][12]

    prep_wf<<<(E_DIM * 12 + 255) / 256, 256, 0, stream>>>(Wf, wfp);
    qkv_proj<<<dim3(T_SEQ / RB, NEC), 256, 0, stream>>>(xe, Wk, bk, Wq, bq, Wv, bv, partQ);
    reduceQ<<<(T_SEQ * (QS / 4)) / 256, 256, 0, stream>>>(partQ, qkvF);
    attn<<<dim3(NIB, NJC), 256, 0, stream>>>(qkvF, part);
    pass2<<<T_SEQ / TR, 256, 0, stream>>>(part, wfp, bf, out);
}

// Round 6
// 193.006 us; speedup vs baseline: 1.8086x; 1.0016x over previous
//
#include <hip/hip_runtime.h>

#define T_SEQ 8192
#define E_DIM 1024
#define QS 36              // padded qkv row: [k 0..10][pad][q 12..22][pad][v 24..34][pad]
#define NEC 8              // E-chunks in qkv projection
#define ECOLS 128          // cols per qkv block
#define KC 64              // cols per LDS sub-chunk
#define C2N 32             // KC/2 column pairs
#define XST 65             // float2 row stride in xP
#define RB 64              // qkv rows per block
#define JCH 64             // attn j-chunk rows
#define NSLOT 64           // part slots (chunk c -> slot c & 63, dual-chunk blocks)
#define RPB 512            // attn rows per block (2 rows/thread)
#define NIB (T_SEQ / RPB)  // 16
#define KVW 24             // compact LDS kv row: [k0..10,pad][v0..10,pad]
#define TR 16              // pass2 rows per block
#define LOG2E 1.4426950408889634f

__device__ __forceinline__ float2 pkfma(float2 a, float2 b, float2 c) {
    return make_float2(fmaf(a.x, b.x, c.x), fmaf(a.y, b.y, c.y));
}
__device__ __forceinline__ float2 f2(float x, float y) { return make_float2(x, y); }

// ws floats (overlaid): qkvF[T][QS] 1.18MB | wfp[E][12] 48KB |
//   region R: partQ[NEC][T][QS] 9.44MB overlaid by part[NSLOT][T][12] 25.2MB
//   (partQ dead after reduceQ; attn runs after -> stream-ordered safe). ~26.4MB

// ---------------------------------------------------------------------------
// K0: pad Wf [E][11] -> [E][12] for coalesced float4 loads in pass2
// ---------------------------------------------------------------------------
__global__ __launch_bounds__(256) void prep_wf(const float* __restrict__ Wf,
                                               float* __restrict__ Wfp) {
    int id = blockIdx.x * 256 + threadIdx.x;
    if (id >= E_DIM * 12) return;
    int e = id / 12, d = id % 12;
    Wfp[id] = (d < 11) ? Wf[(size_t)e * 11 + d] : 0.f;
}

// ---------------------------------------------------------------------------
// K1: qkv projection. 1024 blocks (128 row-blocks x 8 col-chunks) = 4/CU.
// xe staged in LDS column-pair layout (ds_read_b64 per 9 packed FMAs);
// weights wave-uniform -> scalar pipe; staging prefetched 1 sub-chunk ahead.
// ---------------------------------------------------------------------------
__global__ __launch_bounds__(256) void qkv_proj(
    const float* __restrict__ xe,
    const float* __restrict__ Wk, const float* __restrict__ bk,
    const float* __restrict__ Wq, const float* __restrict__ bq,
    const float* __restrict__ Wv, const float* __restrict__ bv,
    float* __restrict__ partQ) {
    const int row0 = blockIdx.x * RB;
    const int ec = blockIdx.y;
    const int lane = threadIdx.x & 63;
    const int wg = __builtin_amdgcn_readfirstlane(threadIdx.x >> 6);

    __shared__ float2 xP[C2N * XST];

    const float* wrow[9]; int col[9]; float bias[9]; bool live[9];
#pragma unroll
    for (int k = 0; k < 9; ++k) {
        int o = wg * 9 + k;
        const float* base; float b = 0.f; int c; bool lv = true;
        if (o < 11)      { base = Wk + (size_t)o * E_DIM;        b = bk[o];      c = o; }
        else if (o < 22) { base = Wq + (size_t)(o - 11) * E_DIM; b = bq[o - 11]; c = o + 1; }
        else if (o < 33) { base = Wv + (size_t)(o - 22) * E_DIM; b = bv[o - 22]; c = o + 2; }
        else             { base = Wk; c = (o == 33) ? 11 : (o == 34) ? 23 : 35; lv = false; }
        wrow[k] = base; col[k] = c; bias[k] = b; live[k] = lv;
    }

    float2 acc[9];
#pragma unroll
    for (int k = 0; k < 9; ++k) acc[k] = f2(0.f, 0.f);

    float4 st[4];
    // staging map: idx -> r = idx>>4 (0..63), c4 = idx&15 (16 float4 per 64-col row)
#define STAGE_LOAD(sub)                                                         \
    {                                                                           \
        const int cb = ec * ECOLS + (sub) * KC;                                 \
        _Pragma("unroll")                                                       \
        for (int t = 0; t < 4; ++t) {                                           \
            int idx = threadIdx.x + t * 256;                                    \
            int r = idx >> 4, c4 = idx & 15;                                    \
            st[t] = *(const float4*)(xe + (size_t)(row0 + r) * E_DIM + cb + c4 * 4); \
        }                                                                       \
    }

    STAGE_LOAD(0);
    for (int sub = 0; sub < ECOLS / KC; ++sub) {
        if (sub) __syncthreads();                 // WAR: prev compute done
#pragma unroll
        for (int t = 0; t < 4; ++t) {
            int idx = threadIdx.x + t * 256;
            int r = idx >> 4, c4 = idx & 15;
            float2* d = &xP[(size_t)(c4 * 2) * XST + r];
            d[0]   = f2(st[t].x, st[t].y);
            d[XST] = f2(st[t].z, st[t].w);
        }
        if (sub + 1 < ECOLS / KC) STAGE_LOAD(sub + 1);
        __syncthreads();

        const int cbase = ec * ECOLS + sub * KC;
#pragma unroll 4
        for (int c2 = 0; c2 < C2N; ++c2) {
            float2 xv = xP[c2 * XST + lane];
            const int c = cbase + 2 * c2;
#pragma unroll
            for (int k = 0; k < 9; ++k) {
                const float2 wv = *(const float2*)(wrow[k] + c);
                acc[k] = pkfma(xv, wv, acc[k]);
            }
        }
    }
#undef STAGE_LOAD

    float* dst = partQ + ((size_t)ec * T_SEQ + row0 + lane) * QS;
#pragma unroll
    for (int k = 0; k < 9; ++k) {
        float v = acc[k].x + acc[k].y + (ec == 0 ? bias[k] : 0.f);
        dst[col[k]] = live[k] ? v : 0.f;
    }
}

// ---------------------------------------------------------------------------
// K2: reduce NEC qkv partial chunks into dense qkvF.
// ---------------------------------------------------------------------------
__global__ __launch_bounds__(256) void reduceQ(const float* __restrict__ partQ,
                                               float* __restrict__ qkvF) {
    const size_t idx = (size_t)blockIdx.x * 256 + threadIdx.x;
    const float4* p = (const float4*)partQ;
    const size_t cs = (size_t)T_SEQ * (QS / 4);
    float4 s = make_float4(0.f, 0.f, 0.f, 0.f);
#pragma unroll
    for (int c = 0; c < NEC; ++c) {
        float4 a = p[idx + (size_t)c * cs];
        s.x += a.x; s.y += a.y; s.z += a.z; s.w += a.w;
    }
    ((float4*)qkvF)[idx] = s;
}

// ---------------------------------------------------------------------------
// K3: causal attention. Block (ib, jc): 256 thr, rows [ib*512, +512) 2/thread,
// processes j-chunks jc*64 and (jc+64)*64 (if in causal range), accumulating
// into the same registers -> one part slot. 1088 active blocks (~4.25/CU,
// ~17 waves/CU resident) hides LDS latency. Compact 24-float kv LDS rows.
// ---------------------------------------------------------------------------
__device__ __forceinline__ void attn_chunk(const float* kv, int j0, int r0,
    const float4& qa0, const float4& qa1, const float4& qa2,
    const float4& qb0, const float4& qb1, const float4& qb2,
    float2& a01, float2& a23, float2& a45, float2& a67, float2& a89, float2& aXL,
    float2& b01, float2& b23, float2& b45, float2& b67, float2& b89, float2& bXL) {
#pragma unroll 2
    for (int jj = 0; jj < JCH; ++jj) {
        const float* kp = kv + jj * KVW;
        const float4 kA = *(const float4*)(kp);
        const float4 kB = *(const float4*)(kp + 4);
        const float4 kC = *(const float4*)(kp + 8);
        const float4 vA = *(const float4*)(kp + 12);
        const float4 vB = *(const float4*)(kp + 16);
        const float4 vC = *(const float4*)(kp + 20);

        float2 sa = pkfma(f2(qa0.x, qa0.y), f2(kA.x, kA.y),
                    pkfma(f2(qa0.z, qa0.w), f2(kA.z, kA.w),
                    pkfma(f2(qa1.x, qa1.y), f2(kB.x, kB.y),
                    pkfma(f2(qa1.z, qa1.w), f2(kB.z, kB.w),
                    pkfma(f2(qa2.x, qa2.y), f2(kC.x, kC.y), f2(0.f, 0.f))))));
        float2 sb = pkfma(f2(qb0.x, qb0.y), f2(kA.x, kA.y),
                    pkfma(f2(qb0.z, qb0.w), f2(kA.z, kA.w),
                    pkfma(f2(qb1.x, qb1.y), f2(kB.x, kB.y),
                    pkfma(f2(qb1.z, qb1.w), f2(kB.z, kB.w),
                    pkfma(f2(qb2.x, qb2.y), f2(kC.x, kC.y), f2(0.f, 0.f))))));
        float pa = exp2f(sa.x + sa.y + qa2.z * kC.z);
        float pb = exp2f(sb.x + sb.y + qb2.z * kC.z);
        const int j = j0 + jj;
        pa = (j <= r0)     ? pa : 0.f;
        pb = (j <= r0 + 1) ? pb : 0.f;
        float2 pa2 = f2(pa, pa), pb2 = f2(pb, pb);
        a01 = pkfma(pa2, f2(vA.x, vA.y), a01);
        a23 = pkfma(pa2, f2(vA.z, vA.w), a23);
        a45 = pkfma(pa2, f2(vB.x, vB.y), a45);
        a67 = pkfma(pa2, f2(vB.z, vB.w), a67);
        a89 = pkfma(pa2, f2(vC.x, vC.y), a89);
        aXL = pkfma(pa2, f2(vC.z, 1.f),  aXL);
        b01 = pkfma(pb2, f2(vA.x, vA.y), b01);
        b23 = pkfma(pb2, f2(vA.z, vA.w), b23);
        b45 = pkfma(pb2, f2(vB.x, vB.y), b45);
        b67 = pkfma(pb2, f2(vB.z, vB.w), b67);
        b89 = pkfma(pb2, f2(vC.x, vC.y), b89);
        bXL = pkfma(pb2, f2(vC.z, 1.f),  bXL);
    }
}

__device__ __forceinline__ void stage_kv(const float* __restrict__ qkvF,
                                         float* kv, int j0) {
    // 64 rows x 6 float4: k at src elems {0,4,8}, v at {24,28,32}; dst f*4.
    for (int idx = threadIdx.x; idx < JCH * 6; idx += 256) {
        int row = idx / 6, f = idx % 6;
        int srcOff = f * 4 + (f >= 3 ? 12 : 0);
        float4 v = *(const float4*)(qkvF + (size_t)(j0 + row) * QS + srcOff);
        *(float4*)(kv + row * KVW + f * 4) = v;
    }
}

__global__ __launch_bounds__(256, 4) void attn(const float* __restrict__ qkvF,
                                               float* __restrict__ part) {
    const int ib = blockIdx.x, jc = blockIdx.y;
    if (jc > 8 * ib + 7) return;                  // chunk A above causal range
    const int row0 = ib * RPB;
    const int r0 = row0 + threadIdx.x * 2;

    const float* qp0 = qkvF + (size_t)r0 * QS + 12;
    const float* qp1 = qp0 + QS;
    float4 qa0 = *(const float4*)(qp0), qa1 = *(const float4*)(qp0 + 4), qa2 = *(const float4*)(qp0 + 8);
    float4 qb0 = *(const float4*)(qp1), qb1 = *(const float4*)(qp1 + 4), qb2 = *(const float4*)(qp1 + 8);
    qa0.x *= LOG2E; qa0.y *= LOG2E; qa0.z *= LOG2E; qa0.w *= LOG2E;
    qa1.x *= LOG2E; qa1.y *= LOG2E; qa1.z *= LOG2E; qa1.w *= LOG2E;
    qa2.x *= LOG2E; qa2.y *= LOG2E; qa2.z *= LOG2E;
    qb0.x *= LOG2E; qb0.y *= LOG2E; qb0.z *= LOG2E; qb0.w *= LOG2E;
    qb1.x *= LOG2E; qb1.y *= LOG2E; qb1.z *= LOG2E; qb1.w *= LOG2E;
    qb2.x *= LOG2E; qb2.y *= LOG2E; qb2.z *= LOG2E;

    float2 a01 = f2(0.f, 0.f), a23 = a01, a45 = a01, a67 = a01, a89 = a01, aXL = a01;
    float2 b01 = a01, b23 = a01, b45 = a01, b67 = a01, b89 = a01, bXL = a01;

    __shared__ float kv[JCH * KVW];

    const int j0A = jc * JCH;
    stage_kv(qkvF, kv, j0A);
    __syncthreads();
    attn_chunk(kv, j0A, r0, qa0, qa1, qa2, qb0, qb1, qb2,
               a01, a23, a45, a67, a89, aXL, b01, b23, b45, b67, b89, bXL);

    const int j0B = (jc + NSLOT) * JCH;
    if (j0B <= row0 + RPB - 1) {                  // uniform per block
        __syncthreads();                          // WAR on kv
        stage_kv(qkvF, kv, j0B);
        __syncthreads();
        attn_chunk(kv, j0B, r0, qa0, qa1, qa2, qb0, qb1, qb2,
                   a01, a23, a45, a67, a89, aXL, b01, b23, b45, b67, b89, bXL);
    }

    float* dst = part + ((size_t)jc * T_SEQ + r0) * 12;
    float4 t;
    t.x = a01.x; t.y = a01.y; t.z = a23.x; t.w = a23.y; *(float4*)(dst + 0)  = t;
    t.x = a45.x; t.y = a45.y; t.z = a67.x; t.w = a67.y; *(float4*)(dst + 4)  = t;
    t.x = a89.x; t.y = a89.y; t.z = aXL.x; t.w = aXL.y; *(float4*)(dst + 8)  = t;
    t.x = b01.x; t.y = b01.y; t.z = b23.x; t.w = b23.y; *(float4*)(dst + 12) = t;
    t.x = b45.x; t.y = b45.y; t.z = b67.x; t.w = b67.y; *(float4*)(dst + 16) = t;
    t.x = b89.x; t.y = b89.y; t.z = bXL.x; t.w = bXL.y; *(float4*)(dst + 20) = t;
}

// ---------------------------------------------------------------------------
// K4: fused partial-reduce + normalize + output GEMM + bias.
// Phase A: 192 thr coalesced slot reduction (8-way unrolled).
// Phase B: thread owns 4 output cols; Wfp rows as 3 coalesced float4.
// ---------------------------------------------------------------------------
__global__ __launch_bounds__(256) void pass2(const float* __restrict__ part,
                                             const float* __restrict__ Wfp,
                                             const float* __restrict__ bf,
                                             float* __restrict__ out) {
    const int t0 = blockIdx.x * TR;
    __shared__ float res[TR][12];
    int cnt = t0 / JCH + 1;                       // uniform per block
    if (cnt > NSLOT) cnt = NSLOT;
    if (threadIdx.x < TR * 12) {
        const float* p = part + (size_t)t0 * 12 + threadIdx.x;
        const size_t S = (size_t)T_SEQ * 12;
        float v[8];
#pragma unroll
        for (int u = 0; u < 8; ++u) v[u] = 0.f;
        int c = 0;
        for (; c + 8 <= cnt; c += 8) {
#pragma unroll
            for (int u = 0; u < 8; ++u) v[u] += p[(size_t)(c + u) * S];
        }
        for (; c < cnt; ++c) v[0] += p[(size_t)c * S];
        float s = ((v[0] + v[1]) + (v[2] + v[3])) + ((v[4] + v[5]) + (v[6] + v[7]));
        const int d = threadIdx.x % 12;
        res[threadIdx.x / 12][d] = (d == 11) ? (1.f / s) : s;
    }
    __syncthreads();

    const int e0 = threadIdx.x * 4;
    float4 wf[4][3];
#pragma unroll
    for (int ee = 0; ee < 4; ++ee) {
        const float4* wp = (const float4*)(Wfp + (size_t)(e0 + ee) * 12);
        wf[ee][0] = wp[0]; wf[ee][1] = wp[1]; wf[ee][2] = wp[2];
    }
    const float4 bv = *(const float4*)(bf + e0);

    for (int r = 0; r < TR; ++r) {
        float rr[12];
#pragma unroll
        for (int d = 0; d < 12; ++d) rr[d] = res[r][d];
        float2 a0 = f2(0.f, 0.f), a1 = a0, a2 = a0, a3 = a0;
#pragma unroll
        for (int d = 0; d < 10; d += 2) {
            float2 rv = f2(rr[d], rr[d + 1]);
            a0 = pkfma(rv, f2(((const float*)&wf[0][0])[d], ((const float*)&wf[0][0])[d + 1]), a0);
            a1 = pkfma(rv, f2(((const float*)&wf[1][0])[d], ((const float*)&wf[1][0])[d + 1]), a1);
            a2 = pkfma(rv, f2(((const float*)&wf[2][0])[d], ((const float*)&wf[2][0])[d + 1]), a2);
            a3 = pkfma(rv, f2(((const float*)&wf[3][0])[d], ((const float*)&wf[3][0])[d + 1]), a3);
        }
        const float rl = rr[11];
        float4 ov;
        ov.x = (a0.x + a0.y + rr[10] * wf[0][2].z) * rl + bv.x;
        ov.y = (a1.x + a1.y + rr[10] * wf[1][2].z) * rl + bv.y;
        ov.z = (a2.x + a2.y + rr[10] * wf[2][2].z) * rl + bv.z;
        ov.w = (a3.x + a3.y + rr[10] * wf[3][2].z) * rl + bv.w;
        *(float4*)(out + (size_t)(t0 + r) * E_DIM + e0) = ov;
    }
}

// ---------------------------------------------------------------------------
extern "C" void kernel_launch(void* const* d_in, const int* in_sizes, int n_in,
                              void* d_out, int out_size, void* d_ws, size_t ws_size,
                              hipStream_t stream) {
    const float* xe = (const float*)d_in[1];
    const float* Wk = (const float*)d_in[2];
    const float* bk = (const float*)d_in[3];
    const float* Wq = (const float*)d_in[4];
    const float* bq = (const float*)d_in[5];
    const float* Wv = (const float*)d_in[6];
    const float* bv = (const float*)d_in[7];
    const float* Wf = (const float*)d_in[8];
    const float* bf = (const float*)d_in[9];
    float* out = (float*)d_out;

    float* qkvF  = (float*)d_ws;                              // [T][QS]
    float* wfp   = qkvF + (size_t)T_SEQ * QS;                 // [E][12]
    float* partQ = wfp + (size_t)E_DIM * 12;                  // [NEC][T][QS]
    float* part  = partQ;                                     // overlay: [NSLOT][T][12]
                                                              // (partQ dead after reduceQ)

    prep_wf<<<(E_DIM * 12 + 255) / 256, 256, 0, stream>>>(Wf, wfp);
    qkv_proj<<<dim3(T_SEQ / RB, NEC), 256, 0, stream>>>(xe, Wk, bk, Wq, bq, Wv, bv, partQ);
    reduceQ<<<(T_SEQ * (QS / 4)) / 256, 256, 0, stream>>>(partQ, qkvF);
    attn<<<dim3(NIB, NSLOT), 256, 0, stream>>>(qkvF, part);
    pass2<<<T_SEQ / TR, 256, 0, stream>>>(part, wfp, bf, out);
}